// Round 7
// baseline (973.805 us; speedup 1.0000x reference)
//
#include <hip/hip_runtime.h>
#include <stdint.h>

typedef unsigned long long u64;
typedef uint32_t u32;

#define NBOX 8192
#define THRF 0.3f
#define EPSF 1e-6f

// ---------- ws layout (bytes) ----------
// order   : [65536,   98304)   int[8192]
// soa     : [98304,  360448)   8 arrays of float[8192]
// sboxes  : [360448, 589824)   float[8192*7]
// keepw   : [589824, 590848)   u64[128]
// diag    : [655360, 720896)   u64[128*64] row-major diagonal 64x64 blocks
// bt      : [1048576, 9437184) u64[128*128*64] bit-transposed 64x64 blocks
//           bt[(br*128+bc)*64 + lane]: bit r = suppress(row 64br+r -> col 64bc+lane)

#define WS_ORDER  65536
#define WS_SOA    98304
#define WS_SBOX   360448
#define WS_KEEPW  589824
#define WS_DIAG   655360
#define WS_BT     1048576

struct DBox { float x1, x2, z1, z2, area, ymin, ymax, h; };

__device__ __forceinline__ DBox derive_box(const float v[7]) {
    float cx = v[0], cy = v[1], cz = v[2];
    float dx = __fmul_rn(v[3], 0.5f);
    float dz = __fmul_rn(v[4], 0.5f);
    float h = v[5], yaw = v[6];
    float c = cosf(yaw), sn = sinf(yaw);
    float A = __fmul_rn(dx, c), B = __fmul_rn(dz, sn);
    float P = __fmul_rn(dx, sn), Q = __fmul_rn(dz, c);
    float mX = fmaxf(fabsf(__fadd_rn(A, B)), fabsf(__fsub_rn(A, B)));
    float mZ = fmaxf(fabsf(__fadd_rn(P, Q)), fabsf(__fsub_rn(P, Q)));
    DBox d;
    d.x1 = __fsub_rn(cx, mX); d.x2 = __fadd_rn(cx, mX);
    d.z1 = __fsub_rn(cz, mZ); d.z2 = __fadd_rn(cz, mZ);
    d.area = __fmul_rn(__fsub_rn(d.x2, d.x1), __fsub_rn(d.z2, d.z1));
    float hh = __fmul_rn(h, 0.5f);
    d.ymin = __fsub_rn(cy, hh); d.ymax = __fadd_rn(cy, hh);
    d.h = h;
    return d;
}

__device__ __forceinline__ float iou_pair(const DBox& a, const DBox& b) {
    float yov = fmaxf(__fsub_rn(fminf(a.ymax, b.ymax), fmaxf(a.ymin, b.ymin)), 0.0f);
    float hun = __fsub_rn(__fadd_rn(a.h, b.h), yov);
    float hr  = __fdiv_rn(yov, __fadd_rn(hun, EPSF));
    float xw  = fmaxf(__fsub_rn(fminf(a.x2, b.x2), fmaxf(a.x1, b.x1)), 0.0f);
    float zw  = fmaxf(__fsub_rn(fminf(a.z2, b.z2), fmaxf(a.z1, b.z1)), 0.0f);
    float inter = __fmul_rn(xw, zw);
    float uni = __fsub_rn(__fadd_rn(a.area, b.area), inter);
    return __fmul_rn(__fdiv_rn(inter, __fadd_rn(uni, EPSF)), hr);
}

__device__ __forceinline__ u64 readlane64(u64 v, int lane) {
    u32 lo = (u32)__builtin_amdgcn_readlane((int)(u32)(v & 0xffffffffull), lane);
    u32 hi = (u32)__builtin_amdgcn_readlane((int)(u32)(v >> 32), lane);
    return ((u64)hi << 32) | (u64)lo;
}

__device__ __forceinline__ float readlane_f(float v, int lane) {
    return __uint_as_float((u32)__builtin_amdgcn_readlane((int)__float_as_uint(v), lane));
}

// K1: fused key-build + O(n^2) rank + gather/derive. 128 blocks x 1 wave.
__global__ __launch_bounds__(64) void sortprep_kernel(const float* __restrict__ s0,
                                                      const float* __restrict__ s1,
                                                      const float* __restrict__ boxes0,
                                                      const float* __restrict__ boxes1,
                                                      int* __restrict__ order,
                                                      float* __restrict__ soa,
                                                      float* __restrict__ sboxes, int N) {
    __shared__ u64 lk[NBOX];           // 64 KiB
    int tid = threadIdx.x;
    for (int j = tid; j < NBOX; j += 64) {
        float sc = (j < N) ? s0[j] : s1[j - N];
        lk[j] = ((u64)(~__float_as_uint(sc)) << 13) | (u32)j;   // scores>=0
    }
    __syncthreads();
    int e = blockIdx.x * 64 + tid;
    u64 k = lk[e];
    int rank = 0;
    const ulonglong2* p2 = (const ulonglong2*)lk;
    #pragma unroll 8
    for (int j = 0; j < NBOX / 2; ++j) {
        ulonglong2 v = p2[j];
        rank += (v.x < k);
        rank += (v.y < k);
    }
    order[rank] = e;
    const float* bp = (e < N) ? boxes0 + (size_t)e * 7 : boxes1 + (size_t)(e - N) * 7;
    float v[7];
    #pragma unroll
    for (int c = 0; c < 7; ++c) { v[c] = bp[c]; sboxes[(size_t)rank * 7 + c] = v[c]; }
    DBox d = derive_box(v);
    soa[0 * NBOX + rank] = d.x1;  soa[1 * NBOX + rank] = d.x2;
    soa[2 * NBOX + rank] = d.z1;  soa[3 * NBOX + rank] = d.z2;
    soa[4 * NBOX + rank] = d.area; soa[5 * NBOX + rank] = d.ymin;
    soa[6 * NBOX + rank] = d.ymax; soa[7 * NBOX + rank] = d.h;
}

// K2: bit-transposed suppression blocks. One wave per 64x64 block pair (br<=bc).
__global__ __launch_bounds__(64) void maskbt_kernel(const float* __restrict__ soa,
                                                    u64* __restrict__ bt,
                                                    u64* __restrict__ diag) {
    int bc = blockIdx.x, br = blockIdx.y;
    if (bc < br) return;
    int lane = threadIdx.x;
    DBox cb;
    cb.x1   = soa[0 * NBOX + 64 * bc + lane];
    cb.x2   = soa[1 * NBOX + 64 * bc + lane];
    cb.z1   = soa[2 * NBOX + 64 * bc + lane];
    cb.z2   = soa[3 * NBOX + 64 * bc + lane];
    cb.area = soa[4 * NBOX + 64 * bc + lane];
    cb.ymin = soa[5 * NBOX + 64 * bc + lane];
    cb.ymax = soa[6 * NBOX + 64 * bc + lane];
    cb.h    = soa[7 * NBOX + 64 * bc + lane];
    float rv[8];
    #pragma unroll
    for (int a = 0; a < 8; ++a) rv[a] = soa[a * NBOX + 64 * br + lane];
    u64 btw = 0, dw = 0;
    bool isdiag = (br == bc);
    for (int r = 0; r < 64; ++r) {
        DBox rb;
        rb.x1   = readlane_f(rv[0], r);
        rb.x2   = readlane_f(rv[1], r);
        rb.z1   = readlane_f(rv[2], r);
        rb.z2   = readlane_f(rv[3], r);
        rb.area = readlane_f(rv[4], r);
        rb.ymin = readlane_f(rv[5], r);
        rb.ymax = readlane_f(rv[6], r);
        rb.h    = readlane_f(rv[7], r);
        float iou = iou_pair(rb, cb);
        bool pred = (iou >= THRF);
        if (isdiag) pred = pred && (lane > r);
        btw |= pred ? (1ull << r) : 0ull;
        if (isdiag) {
            u64 bal = __ballot(pred);
            if (lane == r) dw = bal;
        }
    }
    bt[((size_t)br * 128 + (size_t)bc) * 64 + lane] = btw;
    if (isdiag) diag[(size_t)br * 64 + lane] = dw;
}

// K3: greedy NMS. 16 waves; wave wid owns remv words v = wid+16j (j<8).
// acc (ballot results) are wave-uniform -> SGPRs. Per-lane VGPR state is
// only btp[8] (+ transient btn[8]) and one prefetched diag word -> no spill.
// Per iteration w: issue block(w,v) loads (used next iter, v>w only),
// fold chunk w-1 via one ballot per live word, the owner of word w runs the
// serial decide, one barrier. No memory latency on the critical path.
__global__ __launch_bounds__(1024) void nms_kernel(const u64* __restrict__ bt,
                                                   const u64* __restrict__ diag,
                                                   u64* __restrict__ keepw) {
    __shared__ u64 keptm_sh[2];
    int t = threadIdx.x, lane = t & 63, wid = t >> 6;
    u64 acc[8], btp[8];
    u64 dnext = diag[(size_t)wid * 64 + lane];
    #pragma unroll
    for (int j = 0; j < 8; ++j) {
        int v = wid + 16 * j;
        acc[j] = 0;
        btp[j] = bt[(size_t)v * 64 + lane];          // block(0, v)
    }
    if (wid == 0) {
        u64 keptm = 0, covered = 0, dw = dnext;
        int p = 0;
        while (p < 64) {
            u64 cand = ~covered & ((~0ull) << p);
            if (!cand) break;
            int u = (int)__builtin_ctzll(cand);
            keptm |= 1ull << u;
            covered |= readlane64(dw, u);
            p = u + 1;
        }
        if (lane == 0) { keepw[0] = keptm; keptm_sh[0] = keptm; }
        dnext = diag[(size_t)16 * 64 + lane];
    }
    __syncthreads();
    for (int w = 1; w < 128; ++w) {
        u64 km = keptm_sh[(w - 1) & 1];
        u64 btn[8];
        #pragma unroll
        for (int j = 0; j < 8; ++j) {
            int v = wid + 16 * j;
            btn[j] = 0;
            if (v > w)                                // block(w,v), used at iter w+1
                btn[j] = bt[((size_t)(w * 128 + v)) * 64 + lane];
        }
        #pragma unroll
        for (int j = 0; j < 8; ++j) {
            int v = wid + 16 * j;
            if (v >= w) {                             // fold chunk w-1 into word v
                bool bit = (btp[j] & km) != 0ull;
                acc[j] |= __ballot(bit);
            }
        }
        if ((w & 15) == wid) {
            int jj = w >> 4;
            u64 covered = 0;
            #pragma unroll
            for (int j = 0; j < 8; ++j) if (j == jj) covered = acc[j];
            u64 dw = dnext;
            if (w + 16 < 128) dnext = diag[(size_t)(w + 16) * 64 + lane];
            u64 keptm = 0;
            int p = 0;
            while (p < 64) {
                u64 cand = ~covered & ((~0ull) << p);
                if (!cand) break;
                int u = (int)__builtin_ctzll(cand);
                keptm |= 1ull << u;
                covered |= readlane64(dw, u);
                p = u + 1;
            }
            if (lane == 0) { keepw[w] = keptm; keptm_sh[w & 1] = keptm; }
        }
        #pragma unroll
        for (int j = 0; j < 8; ++j) btp[j] = btn[j];
        __syncthreads();
    }
}

// K4: pair fusion + masking, writes fused (8192x7) then keep (8192) to d_out
__global__ __launch_bounds__(256) void fuse_kernel(const float* __restrict__ boxes1,
                                                   const int* __restrict__ order,
                                                   const float* __restrict__ soa,
                                                   const float* __restrict__ sboxes,
                                                   const u64* __restrict__ keepw,
                                                   float* __restrict__ out, int N) {
    int s = blockIdx.x * 256 + threadIdx.x;
    bool keep = (keepw[s >> 6] >> (s & 63)) & 1ull;
    float res[7];
    if (!keep) {
        #pragma unroll
        for (int c = 0; c < 7; ++c) res[c] = 0.0f;
    } else {
        int o = order[s];
        float a[7];
        #pragma unroll
        for (int c = 0; c < 7; ++c) a[c] = sboxes[(size_t)s * 7 + c];
        if (o >= N) {
            #pragma unroll
            for (int c = 0; c < 7; ++c) res[c] = a[c];
        } else {
            float bv[7];
            #pragma unroll
            for (int c = 0; c < 7; ++c) bv[c] = boxes1[(size_t)o * 7 + c];
            DBox da;
            da.x1 = soa[0 * NBOX + s]; da.x2 = soa[1 * NBOX + s];
            da.z1 = soa[2 * NBOX + s]; da.z2 = soa[3 * NBOX + s];
            da.area = soa[4 * NBOX + s]; da.ymin = soa[5 * NBOX + s];
            da.ymax = soa[6 * NBOX + s]; da.h = soa[7 * NBOX + s];
            DBox db = derive_box(bv);
            float iaa = iou_pair(da, da);
            float iab = iou_pair(da, db);
            float ibb = iou_pair(db, db);
            float im0 = fmaxf(iaa, iab);
            float im1 = fmaxf(iab, ibb);
            bool m0 = im0 > THRF, m1 = im1 > THRF;
            float w0 = m0 ? im0 : 0.0f;
            float w1 = m1 ? im1 : 0.0f;
            float den = __fadd_rn(w0, w1);
            float den_safe = (den == 0.0f) ? 1.0f : den;
            bool any = m0 || m1;
            #pragma unroll
            for (int c = 0; c < 7; ++c) {
                float fw = __fdiv_rn(__fadd_rn(__fmul_rn(a[c], w0), __fmul_rn(bv[c], w1)), den_safe);
                float fm = __fmul_rn(__fadd_rn(a[c], bv[c]), 0.5f);
                res[c] = any ? fw : fm;
            }
        }
    }
    #pragma unroll
    for (int c = 0; c < 7; ++c) out[(size_t)s * 7 + c] = res[c];
    out[(size_t)NBOX * 7 + s] = keep ? 1.0f : 0.0f;
}

extern "C" void kernel_launch(void* const* d_in, const int* in_sizes, int n_in,
                              void* d_out, int out_size, void* d_ws, size_t ws_size,
                              hipStream_t stream) {
    (void)n_in; (void)out_size; (void)ws_size;
    const float* boxes0  = (const float*)d_in[0];
    const float* boxes1  = (const float*)d_in[1];
    const float* scores0 = (const float*)d_in[2];
    const float* scores1 = (const float*)d_in[3];
    int N = in_sizes[2];   // 4096

    char* ws = (char*)d_ws;
    int*   order  = (int*)(ws + WS_ORDER);
    float* soa    = (float*)(ws + WS_SOA);
    float* sboxes = (float*)(ws + WS_SBOX);
    u64*   keepw  = (u64*)(ws + WS_KEEPW);
    u64*   diag   = (u64*)(ws + WS_DIAG);
    u64*   bt     = (u64*)(ws + WS_BT);
    float* out    = (float*)d_out;

    sortprep_kernel<<<NBOX / 64, 64, 0, stream>>>(scores0, scores1, boxes0, boxes1,
                                                  order, soa, sboxes, N);
    maskbt_kernel<<<dim3(128, 128), 64, 0, stream>>>(soa, bt, diag);
    nms_kernel <<<1, 1024, 0, stream>>>(bt, diag, keepw);
    fuse_kernel<<<NBOX / 256, 256, 0, stream>>>(boxes1, order, soa, sboxes, keepw, out, N);
}